// Round 6
// baseline (163.970 us; speedup 1.0000x reference)
//
#include <hip/hip_runtime.h>
#include <math.h>

// Problem constants (fixed by setup_inputs): B=4096, T=512, Q=4
#define T_DIM 512
#define GAMMA_F 0.997f
#define EPS_F 1e-3f
// log2(0.997)
#define LOG2_GAMMA (-0.0043345907f)
#define ROWS_PER_BLOCK 4
#define TILE_T 256

typedef float v4f __attribute__((ext_vector_type(4)));

__device__ __forceinline__ float inv_rescale_f(float x) {
    float s = (x > 0.f) ? 1.f : ((x < 0.f) ? -1.f : 0.f);
    float sqrt_arg = 1.f + 4.f * EPS_F * (fabsf(x) + 1.f + EPS_F);
    float q = (sqrtf(sqrt_arg) - 1.f) * (1.f / (2.f * EPS_F));
    return s * (q * q - 1.f);
}

__device__ __forceinline__ float rescale_f(float x) {
    return copysignf(sqrtf(fabsf(x) + 1.f) - 1.f, x) + EPS_F * x;
}

// 4 rows (b) x 256 t per block; each thread handles the same t in 4 rows.
// 28 independent global loads issued up-front per thread => enough VMEM in
// flight per wave to cover HBM latency (R3/R4 were stuck at VGPR=20 with
// serialized load rounds => ~2 TB/s). Taps via LDS as in R4 (1x HBM traffic).
#define LDS_STRIDE 260
__global__ __launch_bounds__(256, 2) void nstep_qloss_kernel(
    const float* __restrict__ cur_q,    // (B,T,4)
    const float* __restrict__ next_q,   // (B,T,4)
    const float* __restrict__ log_p,    // (B,T)
    const float* __restrict__ reward,   // (B,T,4)
    const float* __restrict__ is_done,  // (B,T)
    const float* __restrict__ mask,     // (B,T)
    float* __restrict__ out)            // (B,T,4)
{
    __shared__ float s_md [ROWS_PER_BLOCK * LDS_STRIDE];   // m*(1-d)
    __shared__ float s_Lmd[ROWS_PER_BLOCK * LDS_STRIDE];   // m*(1-d)*log_p
    __shared__ float s_rx [ROWS_PER_BLOCK * LDS_STRIDE];   // m*reward.x
    __shared__ float s_ry [ROWS_PER_BLOCK * LDS_STRIDE];
    __shared__ float s_rz [ROWS_PER_BLOCK * LDS_STRIDE];
    __shared__ float s_rw [ROWS_PER_BLOCK * LDS_STRIDE];

    int tid  = threadIdx.x;
    int tile = blockIdx.x & (T_DIM / TILE_T - 1);      // 0..1
    int rgrp = blockIdx.x >> 1;                        // 0..B/4-1
    int t0   = tile * TILE_T;
    int t    = t0 + tid;
    int base0 = rgrp * ROWS_PER_BLOCK * T_DIM;         // first row start

    const v4f* rew4 = (const v4f*)reward;
    const v4f* nq4  = (const v4f*)next_q;
    const v4f* cq4  = (const v4f*)cur_q;
    v4f* out4       = (v4f*)out;

    int s4 = (t + 4 < T_DIM) ? t + 4 : T_DIM - 1;      // clamped next index

    // ---- phase 1: all own-element loads for 4 rows, up-front ----
    float m0[4], d0[4], p0[4];
    v4f   r[4], nq[4], cq[4];
#pragma unroll
    for (int k = 0; k < ROWS_PER_BLOCK; ++k) {
        int idx = base0 + k * T_DIM + t;
        m0[k] = mask[idx];
        d0[k] = is_done[idx];
        p0[k] = log_p[idx];
        r[k]  = rew4[idx];
    }
#pragma unroll
    for (int k = 0; k < ROWS_PER_BLOCK; ++k) {
        int rowb = base0 + k * T_DIM;
        nq[k] = nq4[rowb + s4];
        cq[k] = cq4[rowb + t];
    }

    // ---- phase 2: stage into LDS ----
#pragma unroll
    for (int k = 0; k < ROWS_PER_BLOCK; ++k) {
        float md = m0[k] * (1.f - d0[k]);
        int o = k * LDS_STRIDE + tid;
        s_md [o] = md;
        s_Lmd[o] = md * p0[k];
        s_rx [o] = m0[k] * r[k].x;
        s_ry [o] = m0[k] * r[k].y;
        s_rz [o] = m0[k] * r[k].z;
        s_rw [o] = m0[k] * r[k].w;
    }

    // ---- halo: tile slots 256..259 for each row (t clamped to row end) ----
    if (tid < 4 * ROWS_PER_BLOCK) {
        int k = tid >> 2;
        int j = tid & 3;
        int th = t0 + TILE_T + j;
        if (th > T_DIM - 1) th = T_DIM - 1;
        int oh = base0 + k * T_DIM + th;
        float mh = mask[oh];
        float dh = is_done[oh];
        float ph = log_p[oh];
        v4f   rh = rew4[oh];
        float mdh = mh * (1.f - dh);
        int o = k * LDS_STRIDE + TILE_T + j;
        s_md [o] = mdh;
        s_Lmd[o] = mdh * ph;
        s_rx [o] = mh * rh.x;
        s_ry [o] = mh * rh.y;
        s_rz [o] = mh * rh.z;
        s_rw [o] = mh * rh.w;
    }
    __syncthreads();

    // tap weights (validity folded in; same for all rows)
    const float g1 = GAMMA_F;
    const float g2 = g1 * g1;
    const float g3 = g2 * g1;
    const float g4 = g2 * g2;
    float w1 = ((t + 1 < T_DIM) ? 1.f : 0.f) * g1;
    float w2 = ((t + 2 < T_DIM) ? 1.f : 0.f) * g2;
    float w3 = ((t + 3 < T_DIM) ? 1.f : 0.f) * g3;
    float w4 = ((t + 4 < T_DIM) ? 1.f : 0.f) * g4;
    float coeff = exp2f((float)s4 * LOG2_GAMMA);       // gamma^i, absolute idx (faithful)

#pragma unroll
    for (int k = 0; k < ROWS_PER_BLOCK; ++k) {
        int o = k * LDS_STRIDE + tid;
        float a0 = s_rx[o], a1 = s_ry[o], a2 = s_rz[o], a3 = s_rw[o];
        a0 = fmaf(w1, s_rx[o + 1], a0); a1 = fmaf(w1, s_ry[o + 1], a1);
        a2 = fmaf(w1, s_rz[o + 1], a2); a3 = fmaf(w1, s_rw[o + 1], a3);
        a0 = fmaf(w2, s_rx[o + 2], a0); a1 = fmaf(w2, s_ry[o + 2], a1);
        a2 = fmaf(w2, s_rz[o + 2], a2); a3 = fmaf(w2, s_rw[o + 2], a3);
        a0 = fmaf(w3, s_rx[o + 3], a0); a1 = fmaf(w3, s_ry[o + 3], a1);
        a2 = fmaf(w3, s_rz[o + 3], a2); a3 = fmaf(w3, s_rw[o + 3], a3);
        a0 = fmaf(w4, s_rx[o + 4], a0); a1 = fmaf(w4, s_ry[o + 4], a1);
        a2 = fmaf(w4, s_rz[o + 4], a2); a3 = fmaf(w4, s_rw[o + 4], a3);

        float Ls = s_Lmd[o];
        Ls = fmaf(w1, s_Lmd[o + 1], Ls);
        Ls = fmaf(w2, s_Lmd[o + 2], Ls);
        Ls = fmaf(w3, s_Lmd[o + 3], Ls);
        Ls = fmaf(w4, s_Lmd[o + 4], Ls);
        Ls *= GAMMA_F * (1.f / 3.f);                   // extra gamma * inv_num_q

        float g = coeff * s_md[o + 4];                 // m*(1-d) at min(t+4,511)
        float nt0 = g * inv_rescale_f(nq[k].x);
        float nt1 = g * inv_rescale_f(nq[k].y);
        float nt2 = g * inv_rescale_f(nq[k].z);
        float nt3 = g * inv_rescale_f(nq[k].w);

        // q_w = {1, 0.5, 0, 2}; inv_qw = {1, 2, 0, 0.5}
        float tgt0 = rescale_f(a0 + nt0 + 1.0f * Ls);
        float tgt1 = rescale_f(a1 + nt1 + 2.0f * Ls);
        float tgt2 = rescale_f(a2 + nt2);
        float tgt3 = rescale_f(a3 + nt3 + 0.5f * Ls);
        (void)tgt2;

        float hm = 0.5f * m0[k];
        float e0 = cq[k].x - tgt0;
        float e1 = cq[k].y - tgt1;
        float e3 = cq[k].w - tgt3;
        v4f ov;
        ov.x = hm * e0 * e0;
        ov.y = hm * 0.5f * e1 * e1;
        ov.z = 0.f;                                    // q_w[2] == 0
        ov.w = hm * 2.0f * e3 * e3;
        out4[base0 + k * T_DIM + t] = ov;
    }
}

extern "C" void kernel_launch(void* const* d_in, const int* in_sizes, int n_in,
                              void* d_out, int out_size, void* d_ws, size_t ws_size,
                              hipStream_t stream) {
    const float* cur_q   = (const float*)d_in[0];
    const float* next_q  = (const float*)d_in[1];
    const float* log_p   = (const float*)d_in[2];
    const float* reward  = (const float*)d_in[3];
    const float* is_done = (const float*)d_in[4];
    const float* mask    = (const float*)d_in[5];
    float* out = (float*)d_out;

    int BT = in_sizes[2];               // B*T
    int B = BT / T_DIM;
    int blocks = (T_DIM / TILE_T) * (B / ROWS_PER_BLOCK);   // 2 * 1024 = 2048
    hipLaunchKernelGGL(nstep_qloss_kernel, dim3(blocks), dim3(256), 0, stream,
                       cur_q, next_q, log_p, reward, is_done, mask, out);
}

// Round 7
// 157.080 us; speedup vs baseline: 1.0439x; 1.0439x over previous
//
#include <hip/hip_runtime.h>
#include <math.h>

// Problem constants (fixed by setup_inputs): B=4096, T=512, Q=4
#define T_DIM 512
#define GAMMA_F 0.997f
#define EPS_F 1e-3f
// log2(0.997)
#define LOG2_GAMMA (-0.0043345907f)

typedef float v4f __attribute__((ext_vector_type(4)));

__device__ __forceinline__ float inv_rescale_f(float x) {
    float s = (x > 0.f) ? 1.f : ((x < 0.f) ? -1.f : 0.f);
    float sqrt_arg = 1.f + 4.f * EPS_F * (fabsf(x) + 1.f + EPS_F);
    float q = (sqrtf(sqrt_arg) - 1.f) * (1.f / (2.f * EPS_F));
    return s * (q * q - 1.f);
}

__device__ __forceinline__ float rescale_f(float x) {
    return copysignf(sqrtf(fabsf(x) + 1.f) - 1.f, x) + EPS_F * x;
}

// R3 structure (one thread per (b,t), branch-free clamped taps, no LDS) plus a
// sched_barrier(0) between the 22-load block and all consumption: forbids the
// scheduler's register-minimizing "load->use rounds" (R0/R3/R4/R5 all pinned at
// VGPR 20-40 => ~1 load in flight/wave => ~2 TB/s Little's-law ceiling). With
// the batch issued up-front, outstanding bytes/wave ~11 KB => HBM-saturating.
__global__ __launch_bounds__(256) void nstep_qloss_kernel(
    const float* __restrict__ cur_q,    // (B,T,4)
    const float* __restrict__ next_q,   // (B,T,4)
    const float* __restrict__ log_p,    // (B,T)
    const float* __restrict__ reward,   // (B,T,4)
    const float* __restrict__ is_done,  // (B,T)
    const float* __restrict__ mask,     // (B,T)
    float* __restrict__ out,            // (B,T,4)
    int BT)
{
    int idx = blockIdx.x * 256 + threadIdx.x;
    if (idx >= BT) return;
    int t = idx & (T_DIM - 1);
    int base = idx - t;                 // b*T

    // ---- all address math first ----
    int s1 = (t + 1 < T_DIM) ? t + 1 : T_DIM - 1;
    int s2 = (t + 2 < T_DIM) ? t + 2 : T_DIM - 1;
    int s3 = (t + 3 < T_DIM) ? t + 3 : T_DIM - 1;
    int s4 = (t + 4 < T_DIM) ? t + 4 : T_DIM - 1;
    int o0 = idx;
    int o1 = base + s1, o2 = base + s2, o3 = base + s3, o4 = base + s4;

    const v4f* rew4 = (const v4f*)reward;
    const v4f* nq4  = (const v4f*)next_q;
    const v4f* cq4  = (const v4f*)cur_q;
    v4f* out4       = (v4f*)out;

    // ---- load block: 22 independent loads, nothing may sink below the fence ----
    float m0 = mask[o0], m1 = mask[o1], m2 = mask[o2], m3 = mask[o3], m4 = mask[o4];
    float d0 = is_done[o0], d1 = is_done[o1], d2 = is_done[o2], d3 = is_done[o3], d4 = is_done[o4];
    float p0 = log_p[o0], p1 = log_p[o1], p2 = log_p[o2], p3 = log_p[o3], p4 = log_p[o4];
    v4f r0 = rew4[o0], r1 = rew4[o1], r2 = rew4[o2], r3 = rew4[o3], r4 = rew4[o4];
    v4f nq = nq4[o4];
    v4f cq = cq4[o0];
    __builtin_amdgcn_sched_barrier(0);  // pin: all loads issued before any use

    // validity of taps 1..4 (tap 0 always valid)
    float v1 = (t + 1 < T_DIM) ? 1.f : 0.f;
    float v2 = (t + 2 < T_DIM) ? 1.f : 0.f;
    float v3 = (t + 3 < T_DIM) ? 1.f : 0.f;
    float v4v = (t + 4 < T_DIM) ? 1.f : 0.f;

    const float g1 = GAMMA_F;
    const float g2 = g1 * g1;
    const float g3 = g2 * g1;
    const float g4 = g2 * g2;

    float w0 = m0;
    float w1 = v1 * g1 * m1;
    float w2 = v2 * g2 * m2;
    float w3 = v3 * g3 * m3;
    float w4 = v4v * g4 * m4;

    // reward_sum per q
    float a0 = w0 * r0.x; float a1 = w0 * r0.y; float a2 = w0 * r0.z; float a3 = w0 * r0.w;
    a0 = fmaf(w1, r1.x, a0); a1 = fmaf(w1, r1.y, a1); a2 = fmaf(w1, r1.z, a2); a3 = fmaf(w1, r1.w, a3);
    a0 = fmaf(w2, r2.x, a0); a1 = fmaf(w2, r2.y, a1); a2 = fmaf(w2, r2.z, a2); a3 = fmaf(w2, r2.w, a3);
    a0 = fmaf(w3, r3.x, a0); a1 = fmaf(w3, r3.y, a1); a2 = fmaf(w3, r3.z, a2); a3 = fmaf(w3, r3.w, a3);
    a0 = fmaf(w4, r4.x, a0); a1 = fmaf(w4, r4.y, a1); a2 = fmaf(w4, r4.z, a2); a3 = fmaf(w4, r4.w, a3);

    // log_p window sum (q-independent)
    float Ls = w0 * (1.f - d0) * p0;
    Ls = fmaf(w1, (1.f - d1) * p1, Ls);
    Ls = fmaf(w2, (1.f - d2) * p2, Ls);
    Ls = fmaf(w3, (1.f - d3) * p3, Ls);
    Ls = fmaf(w4, (1.f - d4) * p4, Ls);
    Ls *= GAMMA_F * (1.f / 3.f);        // extra gamma factor * inv_num_q

    // next_term: coeff = gamma^i (absolute index, faithful), i = s4
    float coeff = exp2f((float)s4 * LOG2_GAMMA);
    float g = coeff * m4 * (1.f - d4);
    float nt0 = g * inv_rescale_f(nq.x);
    float nt1 = g * inv_rescale_f(nq.y);
    float nt2 = g * inv_rescale_f(nq.z);
    float nt3 = g * inv_rescale_f(nq.w);

    // q_w = {1, 0.5, 0, 2}; inv_qw = {1, 2, 0, 0.5}
    float tgt0 = rescale_f(a0 + nt0 + 1.0f * Ls);
    float tgt1 = rescale_f(a1 + nt1 + 2.0f * Ls);
    float tgt2 = rescale_f(a2 + nt2);
    float tgt3 = rescale_f(a3 + nt3 + 0.5f * Ls);
    (void)tgt2;

    float hm = 0.5f * m0;
    float e0 = cq.x - tgt0;
    float e1 = cq.y - tgt1;
    float e3 = cq.w - tgt3;
    v4f o;
    o.x = hm * e0 * e0;
    o.y = hm * 0.5f * e1 * e1;
    o.z = 0.f;                          // q_w[2] == 0
    o.w = hm * 2.0f * e3 * e3;
    out4[idx] = o;
}

extern "C" void kernel_launch(void* const* d_in, const int* in_sizes, int n_in,
                              void* d_out, int out_size, void* d_ws, size_t ws_size,
                              hipStream_t stream) {
    const float* cur_q   = (const float*)d_in[0];
    const float* next_q  = (const float*)d_in[1];
    const float* log_p   = (const float*)d_in[2];
    const float* reward  = (const float*)d_in[3];
    const float* is_done = (const float*)d_in[4];
    const float* mask    = (const float*)d_in[5];
    float* out = (float*)d_out;

    int BT = in_sizes[2];               // B*T
    int blocks = (BT + 255) / 256;
    hipLaunchKernelGGL(nstep_qloss_kernel, dim3(blocks), dim3(256), 0, stream,
                       cur_q, next_q, log_p, reward, is_done, mask, out, BT);
}